// Round 2
// baseline (226.991 us; speedup 1.0000x reference)
//
#include <hip/hip_runtime.h>
#include <stdint.h>

// Bit-exact f32 vs numpy reference required for label thresholds:
// kill FMA contraction everywhere.
#pragma clang fp contract(off)

#define NB 16       // batch
#define NA 12       // anchors per cell
#define NH 64
#define NW 64
#define NG 64       // gt boxes per batch
#define NN (NA*NH*NW)   // 49152 anchors per batch row
#define NBIN 4096   // rank histogram bins (top 12 of 23 rank bits)
#define CAP 1024    // boundary-bin list capacity per row (expected ~9)

// ws layout (uint32 index):
// [0] pos_cnt  [1] neg_cnt
// [2..18)  rowT (int32)   [18..34) rowBase   [34..50) listCnt
// [64 .. 64+16*4096)   hist
// [65600 .. 65600+16*CAP*2)  boundary lists (u, n) pairs
// [byte WS_LAB_BYTE ..)  lab8 (optional, if ws_size permits)
#define WS_HIST 64
#define WS_LIST 65600
#define WS_ZERO 65600   // zero [0, 65600)
#define WS_LAB_BYTE (65600*4 + NB*CAP*2*4)
#define WS_NEED_LAB ((size_t)WS_LAB_BYTE + (size_t)NB*NN)

__device__ __forceinline__ uint32_t rotl32(uint32_t x, int r) {
    return (x << r) | (x >> (32 - r));
}

// threefry2x32, key = jax.random.key(42) -> (0, 42), partitionable counters:
// x0 = hi(flat_idx)=0, x1 = lo(flat_idx)=i; 32-bit draw = out0 ^ out1.
// Verified bit-exact in round 1 (absmax 0).
__device__ uint32_t threefry_bits(uint32_t idx) {
    const uint32_t ks0 = 0u, ks1 = 42u, ks2 = 0x1BD11BDAu ^ 0u ^ 42u;
    uint32_t x0 = ks0;
    uint32_t x1 = idx + ks1;
#define RND(r) { x0 += x1; x1 = rotl32(x1, r); x1 ^= x0; }
    RND(13) RND(15) RND(26) RND(6)
    x0 += ks1; x1 += ks2 + 1u;
    RND(17) RND(29) RND(16) RND(24)
    x0 += ks2; x1 += ks0 + 2u;
    RND(13) RND(15) RND(26) RND(6)
    x0 += ks0; x1 += ks1 + 3u;
    RND(17) RND(29) RND(16) RND(24)
    x0 += ks1; x1 += ks2 + 4u;
    RND(13) RND(15) RND(26) RND(6)
    x0 += ks2; x1 += ks0 + 5u;
#undef RND
    return x0 ^ x1;
}

__global__ __launch_bounds__(256) void k_zero(uint32_t* __restrict__ w) {
    int i = blockIdx.x * 256 + threadIdx.x;
    if (i < WS_ZERO) w[i] = 0u;
}

// Division-free argmax: candidates are fractions (num, den); ov==0 case is
// represented exactly as 1e-10/1 so that num/den rounds to the reference's
// substituted 1e-10f. Compare by f32 cross-mult with guard band 2^-20:
//   d > band  ==> round(num_g/den_g) >  round(num_b/den_b)  (provable)
//   d < -band ==> strictly smaller
//   |d| <= band and different representation ==> rare fallback: do the two
//   IEEE divisions and compare rounded values (ties keep earlier index).
__global__ __launch_bounds__(256) void k_main(const float4* __restrict__ gt,
                                              const float4* __restrict__ anc,
                                              float* __restrict__ out,
                                              uint32_t* __restrict__ w,
                                              uint8_t* __restrict__ lab8) {
#pragma clang fp contract(off)
    const int b = blockIdx.y;
    const int n = blockIdx.x * 256 + threadIdx.x;
    const int t = threadIdx.x;

    __shared__ float4 sgv[NG];    // (gx0, gy0, gx1, gy1)
    __shared__ float  sgar[NG];   // gt area
    __shared__ float4 sg0[NG];    // batch-0 boxes (reference gt_flat indexing bug)
    __shared__ float  sout[256 * 5];
    if (t < NG) {
        float4 g = gt[b * NG + t];
        sgv[t] = make_float4(g.x, g.y, g.x + g.z, g.y + g.w);
        sgar[t] = g.z * g.w;
    } else if (t < 2 * NG) {
        sg0[t - NG] = gt[t - NG];
    }
    __syncthreads();

    float4 a = anc[n];
    float ax1 = a.x + a.z;
    float ay1 = a.y + a.w;
    float aar = a.z * a.w;
    bool keep = (a.x >= 0.f) && (a.y >= 0.f) && (a.z >= 0.f) && (a.w >= 0.f)
             && (a.x <= 63.f) && (a.y <= 63.f)
             && ((ax1 - 1.0f) <= 63.f) && ((ay1 - 1.0f) <= 63.f);

    float nb_, db_;            // best fraction
    int ib_ = 0;
    {
        float4 gv = sgv[0];
        float iw = fmaxf(0.0f, fminf(ax1, gv.z) - fmaxf(a.x, gv.x));
        float ih = fmaxf(0.0f, fminf(ay1, gv.w) - fmaxf(a.y, gv.y));
        float inter = iw * ih;
        float uni = (aar + sgar[0]) - inter;
        nb_ = inter; db_ = uni;
        if (inter == 0.0f) { nb_ = 1e-10f; db_ = 1.0f; }
    }
#pragma unroll 4
    for (int g = 1; g < NG; ++g) {
        float4 gv = sgv[g];
        float iw = fmaxf(0.0f, fminf(ax1, gv.z) - fmaxf(a.x, gv.x));
        float ih = fmaxf(0.0f, fminf(ay1, gv.w) - fmaxf(a.y, gv.y));
        float inter = iw * ih;
        float uni = (aar + sgar[g]) - inter;
        float ng_ = inter, dg_ = uni;
        if (inter == 0.0f) { ng_ = 1e-10f; dg_ = 1.0f; }

        float p = ng_ * db_;
        float q = nb_ * dg_;
        float d_ = p - q;
        float band = 0x1p-20f * fmaxf(p, q);
        bool same = (ng_ == nb_) && (dg_ == db_);   // identical fraction (e.g. both empty)
        bool nearby = (!same) && (fabsf(d_) <= band);
        bool win;
        if (__builtin_expect(nearby, 0)) {
            float ovg = ng_ / dg_;
            float ovb = nb_ / db_;
            win = ovg > ovb;                        // rounded compare, tie keeps earlier
        } else {
            win = d_ > band;                        // same => d_==0 => false (keep earlier)
        }
        if (win) { nb_ = ng_; db_ = dg_; ib_ = g; }
    }
    float best = nb_ / db_;    // == reference max_ov, bit-exact

    float label = -1.0f;
    if (keep) label = (best >= 0.7f) ? 1.0f : ((best <= 0.3f) ? 0.0f : -1.0f);

    if (keep && best > 0.7f) atomicAdd(&w[0], 1u);   // pos_cnt (strict >)
    if (keep && best < 0.3f) atomicAdd(&w[1], 1u);   // neg_cnt (strict <)

    float t0 = 0.f, t1 = 0.f, t2 = 0.f, t3 = 0.f;
    if (keep) {
        float4 g0 = sg0[ib_];                 // always batch-0 (ref bug)
        t0 = a.x - g0.x / 16.0f;
        t1 = a.y - g0.y / 16.0f;
        t2 = a.z - g0.z / 16.0f;
        t3 = a.w - g0.w / 16.0f;
    }

    // Stage to LDS (stride 5, coprime with 32 banks -> conflict-free),
    // then fully-coalesced full-line stores.
    sout[t * 5 + 0] = label;
    sout[t * 5 + 1] = t0; sout[t * 5 + 2] = t1;
    sout[t * 5 + 3] = t2; sout[t * 5 + 4] = t3;

    if (label == 0.0f) {
        uint32_t u = threefry_bits((uint32_t)(b * NN + n)) >> 9;  // 23-bit rank key
        atomicAdd(&w[WS_HIST + b * NBIN + (u >> 11)], 1u);
    }
    if (lab8) lab8[b * NN + n] = (label == 0.0f) ? 2 : ((label == 1.0f) ? 1 : 0);

    __syncthreads();
    float* ob = out + ((size_t)b * NN + (size_t)blockIdx.x * 256) * 5;
#pragma unroll
    for (int k = 0; k < 5; ++k) ob[k * 256 + t] = sout[k * 256 + t];
}

__global__ __launch_bounds__(256) void k_scan(uint32_t* __restrict__ w) {
    const int b = blockIdx.x;
    const uint32_t* hist = w + WS_HIST + b * NBIN;
    __shared__ uint32_t csum[256];
    uint32_t pos = w[0];
    uint32_t cutoff = 3u * pos; if (cutoff < 1u) cutoff = 1u;
    int t = threadIdx.x;
    uint32_t s = 0;
    for (int k = 0; k < 16; ++k) s += hist[t * 16 + k];
    csum[t] = s;
    __syncthreads();
    if (t == 0) {
        uint32_t cum = 0; int tc = -1;
        for (int c = 255; c >= 0; --c) {
            if (cum + csum[c] >= cutoff) { tc = c; break; }
            cum += csum[c];
        }
        int T = -1; uint32_t base = 0;
        if (tc >= 0) {
            for (int k = 15; k >= 0; --k) {
                int bin = tc * 16 + k;
                uint32_t h = hist[bin];
                if (cum + h >= cutoff) { T = bin; base = cum; break; }
                cum += h;
            }
        }
        ((int32_t*)w)[2 + b] = T;   // -1: fewer than cutoff label-0 -> keep all
        w[18 + b] = base;           // exact ranks above bin T
        w[34 + b] = 0;              // boundary list count
    }
}

__global__ __launch_bounds__(256) void k_disable(float* __restrict__ out,
                                                 uint32_t* __restrict__ w,
                                                 const uint8_t* __restrict__ lab8) {
    const int b = blockIdx.y;
    const int n = blockIdx.x * 256 + threadIdx.x;
    uint32_t pos = w[0], neg = w[1];
    uint32_t cutoff = 3u * pos; if (cutoff < 1u) cutoff = 1u;
    if (neg <= cutoff) return;           // global gate
    int T = ((int32_t*)w)[2 + b];
    if (T < 0) return;
    size_t base = ((size_t)b * NN + n) * 5;
    bool is0;
    if (lab8) is0 = (lab8[b * NN + n] == 2);
    else      is0 = (out[base] == 0.0f);
    if (!is0) return;                    // only label-0 anchors ranked
    uint32_t u = threefry_bits((uint32_t)(b * NN + n)) >> 9;
    int bin = (int)(u >> 11);
    if (bin > T) return;                 // rank < cutoff: stays 0
    if (bin < T) { out[base] = -1.0f; return; }   // rank >= cutoff: disabled
    uint32_t idx = atomicAdd(&w[34 + b], 1u);     // boundary bin: exact resolve
    if (idx < CAP) {
        uint32_t* lst = w + WS_LIST + ((size_t)b * CAP + idx) * 2;
        lst[0] = u; lst[1] = (uint32_t)n;
    }
}

__global__ __launch_bounds__(256) void k_resolve(float* __restrict__ out,
                                                 uint32_t* __restrict__ w) {
    const int b = blockIdx.x;
    uint32_t pos = w[0], neg = w[1];
    uint32_t cutoff = 3u * pos; if (cutoff < 1u) cutoff = 1u;
    if (neg <= cutoff) return;
    uint32_t cnt = w[34 + b]; if (cnt > CAP) cnt = CAP;
    uint32_t baseRank = w[18 + b];
    const uint32_t* lst = w + WS_LIST + (size_t)b * CAP * 2;
    for (uint32_t i = threadIdx.x; i < cnt; i += 256) {
        uint32_t u = lst[i * 2], n = lst[i * 2 + 1];
        uint32_t r = baseRank;
        for (uint32_t j = 0; j < cnt; ++j) {
            uint32_t uj = lst[j * 2], nj = lst[j * 2 + 1];
            // descending u, ties by smaller index first (stable argsort)
            r += (uj > u || (uj == u && nj < n)) ? 1u : 0u;
        }
        if (r >= cutoff) out[((size_t)b * NN + n) * 5] = -1.0f;
    }
}

extern "C" void kernel_launch(void* const* d_in, const int* in_sizes, int n_in,
                              void* d_out, int out_size, void* d_ws, size_t ws_size,
                              hipStream_t stream) {
    // d_in[0] = cls_scores (shape-relevant only, never read)
    const float4* gt  = (const float4*)d_in[1];
    const float4* anc = (const float4*)d_in[2];
    float* out = (float*)d_out;
    uint32_t* w = (uint32_t*)d_ws;
    uint8_t* lab8 = (ws_size >= WS_NEED_LAB) ? ((uint8_t*)d_ws + WS_LAB_BYTE)
                                             : (uint8_t*)nullptr;

    k_zero<<<dim3((WS_ZERO + 255) / 256), 256, 0, stream>>>(w);
    k_main<<<dim3(NN / 256, NB), 256, 0, stream>>>(gt, anc, out, w, lab8);
    k_scan<<<dim3(NB), 256, 0, stream>>>(w);
    k_disable<<<dim3(NN / 256, NB), 256, 0, stream>>>(out, w, lab8);
    k_resolve<<<dim3(NB), 256, 0, stream>>>(out, w);
}

// Round 3
// 117.937 us; speedup vs baseline: 1.9247x; 1.9247x over previous
//
#include <hip/hip_runtime.h>
#include <stdint.h>

// Bit-exact f32 vs numpy reference required for label thresholds:
// kill FMA contraction everywhere.
#pragma clang fp contract(off)

#define NB 16       // batch
#define NA 12       // anchors per cell
#define NH 64
#define NW 64
#define NG 64       // gt boxes per batch
#define NN (NA*NH*NW)   // 49152 anchors per batch row
#define NBLK (NN/256)   // 192 blocks per batch row
#define NBIN 4096   // rank histogram bins (top 12 of 23 rank bits)
#define CAP 1024    // boundary-bin list capacity per row (expected ~9)

// ws layout (uint32 index):
// [0] pos_cnt  [1] neg_cnt   (written by k_scan block 0)
// [2..18)  rowT (int32)   [18..34) rowBase   [34..50) listCnt
// [64 .. 64+16*4096)        hist
// [65600 .. 65600+3072)     per-block packed (pos<<16 | neg) partials
// [71744 .. 71744+16*CAP*2) boundary lists (u, n) pairs
// [byte WS_LAB_BYTE ..)     lab8 (optional, if ws_size permits)
#define WS_HIST 64
#define WS_PART 65600
#define WS_LIST 71744
#define WS_ZERO 65600   // zero [0, 65600): head + hist (partials need no zero)
#define WS_LAB_BYTE ((WS_LIST + NB*CAP*2) * 4)
#define WS_NEED_LAB ((size_t)WS_LAB_BYTE + (size_t)NB*NN)

__device__ __forceinline__ uint32_t rotl32(uint32_t x, int r) {
    return (x << r) | (x >> (32 - r));
}

// threefry2x32, key = jax.random.key(42) -> (0, 42), partitionable counters:
// x0 = hi(flat_idx)=0, x1 = lo(flat_idx)=i; 32-bit draw = out0 ^ out1.
// Verified bit-exact in round 1 (absmax 0).
__device__ uint32_t threefry_bits(uint32_t idx) {
    const uint32_t ks0 = 0u, ks1 = 42u, ks2 = 0x1BD11BDAu ^ 0u ^ 42u;
    uint32_t x0 = ks0;
    uint32_t x1 = idx + ks1;
#define RND(r) { x0 += x1; x1 = rotl32(x1, r); x1 ^= x0; }
    RND(13) RND(15) RND(26) RND(6)
    x0 += ks1; x1 += ks2 + 1u;
    RND(17) RND(29) RND(16) RND(24)
    x0 += ks2; x1 += ks0 + 2u;
    RND(13) RND(15) RND(26) RND(6)
    x0 += ks0; x1 += ks1 + 3u;
    RND(17) RND(29) RND(16) RND(24)
    x0 += ks1; x1 += ks2 + 4u;
    RND(13) RND(15) RND(26) RND(6)
    x0 += ks2; x1 += ks0 + 5u;
#undef RND
    return x0 ^ x1;
}

__global__ __launch_bounds__(256) void k_zero(uint32_t* __restrict__ w) {
    int i = blockIdx.x * 256 + threadIdx.x;
    if (i < WS_ZERO) w[i] = 0u;
}

// Division-free argmax (verified bit-exact in R1/R2): fractions (num, den),
// ov==0 represented exactly as 1e-10/1; cross-mult compare with 2^-20 guard
// band, rare in-band fallback does the two IEEE divisions.
__global__ __launch_bounds__(256) void k_main(const float4* __restrict__ gt,
                                              const float4* __restrict__ anc,
                                              float* __restrict__ out,
                                              uint32_t* __restrict__ w,
                                              uint8_t* __restrict__ lab8) {
#pragma clang fp contract(off)
    const int b = blockIdx.y;
    const int n = blockIdx.x * 256 + threadIdx.x;
    const int t = threadIdx.x;

    __shared__ float4 sgv[NG];    // (gx0, gy0, gx1, gy1)
    __shared__ float  sgar[NG];   // gt area
    __shared__ float4 sg0[NG];    // batch-0 boxes (reference gt_flat indexing bug)
    __shared__ float  sout[256 * 5];
    __shared__ uint32_t sred[4];  // per-wave packed (pos<<16 | neg)
    if (t < NG) {
        float4 g = gt[b * NG + t];
        sgv[t] = make_float4(g.x, g.y, g.x + g.z, g.y + g.w);
        sgar[t] = g.z * g.w;
    } else if (t < 2 * NG) {
        sg0[t - NG] = gt[t - NG];
    }
    __syncthreads();

    float4 a = anc[n];
    float ax1 = a.x + a.z;
    float ay1 = a.y + a.w;
    float aar = a.z * a.w;
    bool keep = (a.x >= 0.f) && (a.y >= 0.f) && (a.z >= 0.f) && (a.w >= 0.f)
             && (a.x <= 63.f) && (a.y <= 63.f)
             && ((ax1 - 1.0f) <= 63.f) && ((ay1 - 1.0f) <= 63.f);

    float nb_, db_;            // best fraction
    int ib_ = 0;
    {
        float4 gv = sgv[0];
        float iw = fmaxf(0.0f, fminf(ax1, gv.z) - fmaxf(a.x, gv.x));
        float ih = fmaxf(0.0f, fminf(ay1, gv.w) - fmaxf(a.y, gv.y));
        float inter = iw * ih;
        float uni = (aar + sgar[0]) - inter;
        nb_ = inter; db_ = uni;
        if (inter == 0.0f) { nb_ = 1e-10f; db_ = 1.0f; }
    }
#pragma unroll 4
    for (int g = 1; g < NG; ++g) {
        float4 gv = sgv[g];
        float iw = fmaxf(0.0f, fminf(ax1, gv.z) - fmaxf(a.x, gv.x));
        float ih = fmaxf(0.0f, fminf(ay1, gv.w) - fmaxf(a.y, gv.y));
        float inter = iw * ih;
        float uni = (aar + sgar[g]) - inter;
        float ng_ = inter, dg_ = uni;
        if (inter == 0.0f) { ng_ = 1e-10f; dg_ = 1.0f; }

        float p = ng_ * db_;
        float q = nb_ * dg_;
        float d_ = p - q;
        float band = 0x1p-20f * fmaxf(p, q);
        bool same = (ng_ == nb_) && (dg_ == db_);
        bool nearby = (!same) && (fabsf(d_) <= band);
        bool win;
        if (__builtin_expect(nearby, 0)) {
            float ovg = ng_ / dg_;
            float ovb = nb_ / db_;
            win = ovg > ovb;                        // rounded compare, tie keeps earlier
        } else {
            win = d_ > band;                        // same => d_==0 => false (keep earlier)
        }
        if (win) { nb_ = ng_; db_ = dg_; ib_ = g; }
    }
    float best = nb_ / db_;    // == reference max_ov, bit-exact

    float label = -1.0f;
    if (keep) label = (best >= 0.7f) ? 1.0f : ((best <= 0.3f) ? 0.0f : -1.0f);

    // pos/neg counting: ballot + LDS combine + ONE plain store per block to a
    // distinct slot. No global atomics (the R2 wall: every wave hit the same
    // 64B line -> cross-XCD atomic serialization ~120us).
    uint64_t bp = __ballot(keep && (best > 0.7f));   // pos (strict >)
    uint64_t bn = __ballot(keep && (best < 0.3f));   // neg (strict <)
    if ((t & 63) == 0)
        sred[t >> 6] = ((uint32_t)__popcll(bp) << 16) | (uint32_t)__popcll(bn);

    float t0 = 0.f, t1 = 0.f, t2 = 0.f, t3 = 0.f;
    if (keep) {
        float4 g0 = sg0[ib_];                 // always batch-0 (ref bug)
        t0 = a.x - g0.x / 16.0f;
        t1 = a.y - g0.y / 16.0f;
        t2 = a.z - g0.z / 16.0f;
        t3 = a.w - g0.w / 16.0f;
    }

    // Stage to LDS (stride 5, coprime with 32 banks), then coalesced stores.
    sout[t * 5 + 0] = label;
    sout[t * 5 + 1] = t0; sout[t * 5 + 2] = t1;
    sout[t * 5 + 3] = t2; sout[t * 5 + 4] = t3;

    if (label == 0.0f) {
        uint32_t u = threefry_bits((uint32_t)(b * NN + n)) >> 9;  // 23-bit rank key
        atomicAdd(&w[WS_HIST + b * NBIN + (u >> 11)], 1u);
    }
    if (lab8) lab8[b * NN + n] = (label == 0.0f) ? 2 : ((label == 1.0f) ? 1 : 0);

    __syncthreads();
    if (t == 0)
        w[WS_PART + b * NBLK + blockIdx.x] = sred[0] + sred[1] + sred[2] + sred[3];
    float* ob = out + ((size_t)b * NN + (size_t)blockIdx.x * 256) * 5;
#pragma unroll
    for (int k = 0; k < 5; ++k) ob[k * 256 + t] = sout[k * 256 + t];
}

__global__ __launch_bounds__(256) void k_scan(uint32_t* __restrict__ w) {
    const int b = blockIdx.x;
    const int t = threadIdx.x;
    const uint32_t* hist = w + WS_HIST + b * NBIN;
    __shared__ uint32_t csum[256];
    __shared__ uint32_t rp[256], rn[256];

    // Reduce the 3072 per-block packed partials -> pos/neg (each scan block
    // computes them redundantly; block 0 publishes to w[0], w[1]).
    uint32_t sp = 0, sn = 0;
    for (int i = t; i < NB * NBLK; i += 256) {
        uint32_t v = w[WS_PART + i];
        sp += v >> 16; sn += v & 0xFFFFu;
    }
    rp[t] = sp; rn[t] = sn;
    __syncthreads();
    for (int s = 128; s > 0; s >>= 1) {
        if (t < s) { rp[t] += rp[t + s]; rn[t] += rn[t + s]; }
        __syncthreads();
    }
    uint32_t pos = rp[0];
    if (b == 0 && t == 0) { w[0] = rp[0]; w[1] = rn[0]; }

    uint32_t cutoff = 3u * pos; if (cutoff < 1u) cutoff = 1u;
    uint32_t s = 0;
    for (int k = 0; k < 16; ++k) s += hist[t * 16 + k];
    csum[t] = s;
    __syncthreads();
    if (t == 0) {
        uint32_t cum = 0; int tc = -1;
        for (int c = 255; c >= 0; --c) {
            if (cum + csum[c] >= cutoff) { tc = c; break; }
            cum += csum[c];
        }
        int T = -1; uint32_t base = 0;
        if (tc >= 0) {
            for (int k = 15; k >= 0; --k) {
                int bin = tc * 16 + k;
                uint32_t h = hist[bin];
                if (cum + h >= cutoff) { T = bin; base = cum; break; }
                cum += h;
            }
        }
        ((int32_t*)w)[2 + b] = T;   // -1: fewer than cutoff label-0 -> keep all
        w[18 + b] = base;           // exact ranks above bin T
        w[34 + b] = 0;              // boundary list count
    }
}

__global__ __launch_bounds__(256) void k_disable(float* __restrict__ out,
                                                 uint32_t* __restrict__ w,
                                                 const uint8_t* __restrict__ lab8) {
    const int b = blockIdx.y;
    const int n = blockIdx.x * 256 + threadIdx.x;
    uint32_t pos = w[0], neg = w[1];
    uint32_t cutoff = 3u * pos; if (cutoff < 1u) cutoff = 1u;
    if (neg <= cutoff) return;           // global gate
    int T = ((int32_t*)w)[2 + b];
    if (T < 0) return;
    size_t base = ((size_t)b * NN + n) * 5;
    bool is0;
    if (lab8) is0 = (lab8[b * NN + n] == 2);
    else      is0 = (out[base] == 0.0f);
    if (!is0) return;                    // only label-0 anchors ranked
    uint32_t u = threefry_bits((uint32_t)(b * NN + n)) >> 9;
    int bin = (int)(u >> 11);
    if (bin > T) return;                 // rank < cutoff: stays 0
    if (bin < T) { out[base] = -1.0f; return; }   // rank >= cutoff: disabled
    uint32_t idx = atomicAdd(&w[34 + b], 1u);     // boundary bin: exact resolve
    if (idx < CAP) {
        uint32_t* lst = w + WS_LIST + ((size_t)b * CAP + idx) * 2;
        lst[0] = u; lst[1] = (uint32_t)n;
    }
}

__global__ __launch_bounds__(256) void k_resolve(float* __restrict__ out,
                                                 uint32_t* __restrict__ w) {
    const int b = blockIdx.x;
    uint32_t pos = w[0], neg = w[1];
    uint32_t cutoff = 3u * pos; if (cutoff < 1u) cutoff = 1u;
    if (neg <= cutoff) return;
    uint32_t cnt = w[34 + b]; if (cnt > CAP) cnt = CAP;
    uint32_t baseRank = w[18 + b];
    const uint32_t* lst = w + WS_LIST + (size_t)b * CAP * 2;
    for (uint32_t i = threadIdx.x; i < cnt; i += 256) {
        uint32_t u = lst[i * 2], n = lst[i * 2 + 1];
        uint32_t r = baseRank;
        for (uint32_t j = 0; j < cnt; ++j) {
            uint32_t uj = lst[j * 2], nj = lst[j * 2 + 1];
            // descending u, ties by smaller index first (stable argsort)
            r += (uj > u || (uj == u && nj < n)) ? 1u : 0u;
        }
        if (r >= cutoff) out[((size_t)b * NN + n) * 5] = -1.0f;
    }
}

extern "C" void kernel_launch(void* const* d_in, const int* in_sizes, int n_in,
                              void* d_out, int out_size, void* d_ws, size_t ws_size,
                              hipStream_t stream) {
    // d_in[0] = cls_scores (shape-relevant only, never read)
    const float4* gt  = (const float4*)d_in[1];
    const float4* anc = (const float4*)d_in[2];
    float* out = (float*)d_out;
    uint32_t* w = (uint32_t*)d_ws;
    uint8_t* lab8 = (ws_size >= WS_NEED_LAB) ? ((uint8_t*)d_ws + WS_LAB_BYTE)
                                             : (uint8_t*)nullptr;

    k_zero<<<dim3((WS_ZERO + 255) / 256), 256, 0, stream>>>(w);
    k_main<<<dim3(NBLK, NB), 256, 0, stream>>>(gt, anc, out, w, lab8);
    k_scan<<<dim3(NB), 256, 0, stream>>>(w);
    k_disable<<<dim3(NBLK, NB), 256, 0, stream>>>(out, w, lab8);
    k_resolve<<<dim3(NB), 256, 0, stream>>>(out, w);
}